// Round 1
// baseline (513.458 us; speedup 1.0000x reference)
//
#include <hip/hip_runtime.h>

// CropPrompter: fused resize+crop bilinear sampling.
// x: [B=8, C=3, T=16, H=512, W=512] fp32
// out: [8, 3, 16, 224, 224] fp32
// Per-clip params via cam_views[b] -> {resize, y_offset, x_offset}[3].

#define CROP   224
#define HSZ    512
#define QPR    56              // float4 quads per output row (224/4)
#define IMGS   (8 * 3 * 16)    // 384 independent HxW slices
#define TOTAL_THREADS (IMGS * CROP * QPR)   // 4,816,896

__global__ __launch_bounds__(256) void crop_prompter_kernel(
    const float* __restrict__ x,
    const int*   __restrict__ cam_views,
    const float* __restrict__ resize,
    const float* __restrict__ y_off,
    const float* __restrict__ x_off,
    float*       __restrict__ out)
{
    const int tid = blockIdx.x * blockDim.x + threadIdx.x;

    const int q   = tid % QPR;             // which float4 along sx
    const int t1  = tid / QPR;
    const int sy  = t1 % CROP;             // output row
    const int img = t1 / CROP;             // b*48 + c*16 + t
    const int b   = img / 48;              // C*T = 48

    // Per-clip learned params (tiny, L1-broadcast).
    const int v = cam_views[b];
    const float r  = floorf(fminf(fmaxf(resize[v], 512.0f), 1024.0f));
    const float yo = floorf(fminf(fmaxf(y_off[v], 0.0f), r - 224.0f));
    const float xo = floorf(fminf(fmaxf(x_off[v], 0.0f), r - 224.0f));
    const float scale = 512.0f / r;        // H / rb, fp32 like the reference

    // y coords (once per thread)
    float srcy = (yo + (float)sy + 0.5f) * scale - 0.5f;
    srcy = fmaxf(srcy, 0.0f);
    int y0 = (int)floorf(srcy);
    y0 = min(max(y0, 0), HSZ - 1);
    const int y1 = min(y0 + 1, HSZ - 1);
    const float wy = srcy - (float)y0;

    const float* __restrict__ row0 = x + ((size_t)img * HSZ + (size_t)y0) * HSZ;
    const float* __restrict__ row1 = x + ((size_t)img * HSZ + (size_t)y1) * HSZ;

    float4 res;
    float* rp = reinterpret_cast<float*>(&res);

#pragma unroll
    for (int j = 0; j < 4; ++j) {
        const int sx = q * 4 + j;
        float srcx = (xo + (float)sx + 0.5f) * scale - 0.5f;
        srcx = fmaxf(srcx, 0.0f);
        int x0 = (int)floorf(srcx);
        x0 = min(max(x0, 0), HSZ - 1);
        const int x1 = min(x0 + 1, HSZ - 1);
        const float wx = srcx - (float)x0;

        const float v00 = row0[x0];
        const float v01 = row0[x1];
        const float v10 = row1[x0];
        const float v11 = row1[x1];

        // rows = top*(1-wy) + bot*wy; out = rows[x0]*(1-wx) + rows[x1]*wx
        const float left  = v00 * (1.0f - wy) + v10 * wy;
        const float right = v01 * (1.0f - wy) + v11 * wy;
        rp[j] = left * (1.0f - wx) + right * wx;
    }

    reinterpret_cast<float4*>(out)[tid] = res;
}

extern "C" void kernel_launch(void* const* d_in, const int* in_sizes, int n_in,
                              void* d_out, int out_size, void* d_ws, size_t ws_size,
                              hipStream_t stream) {
    const float* x         = (const float*)d_in[0];
    const int*   cam_views = (const int*)  d_in[1];
    const float* resize    = (const float*)d_in[2];
    const float* y_off     = (const float*)d_in[3];
    const float* x_off     = (const float*)d_in[4];
    float* out = (float*)d_out;

    const int block = 256;
    const int grid  = TOTAL_THREADS / block;  // 18,816 exactly, no tail

    crop_prompter_kernel<<<grid, block, 0, stream>>>(
        x, cam_views, resize, y_off, x_off, out);
}

// Round 2
// 487.682 us; speedup vs baseline: 1.0529x; 1.0529x over previous
//
#include <hip/hip_runtime.h>

// CropPrompter: fused resize+crop bilinear sampling.
// x: [B=8, C=3, T=16, H=512, W=512] fp32
// out: [8, 3, 16, 224, 224] fp32
// Per-clip params via cam_views[b] -> {resize, y_offset, x_offset}[3].
//
// Key structural fact: scale = 512/r in [0.5, 1], so x1 == x0+1 except at the
// right clamp edge -> each (v00,v01) pair is 2 consecutive floats = one 8B load.

#define CROP   224
#define HSZ    512
#define QPR    56              // float4 quads per output row (224/4)
#define IMGS   (8 * 3 * 16)    // 384 independent HxW slices
#define TOTAL_THREADS (IMGS * CROP * QPR)   // 4,816,896

__global__ __launch_bounds__(256) void crop_prompter_kernel(
    const float* __restrict__ x,
    const int*   __restrict__ cam_views,
    const float* __restrict__ resize,
    const float* __restrict__ y_off,
    const float* __restrict__ x_off,
    float*       __restrict__ out)
{
    const int tid = blockIdx.x * blockDim.x + threadIdx.x;

    const int q   = tid % QPR;             // which float4 along sx
    const int t1  = tid / QPR;
    const int sy  = t1 % CROP;             // output row
    const int img = t1 / CROP;             // b*48 + c*16 + t
    const int b   = img / 48;              // C*T = 48

    // Per-clip learned params (tiny, L1/L2-broadcast; b is block-uniform
    // almost everywhere -> scalarized).
    const int v = cam_views[b];
    const float r  = floorf(fminf(fmaxf(resize[v], 512.0f), 1024.0f));
    const float yo = floorf(fminf(fmaxf(y_off[v], 0.0f), r - 224.0f));
    const float xo = floorf(fminf(fmaxf(x_off[v], 0.0f), r - 224.0f));
    const float scale = 512.0f / r;        // H / rb, fp32 like the reference

    // y coords (once per thread)
    float srcy = (yo + (float)sy + 0.5f) * scale - 0.5f;
    srcy = fmaxf(srcy, 0.0f);
    int y0 = (int)floorf(srcy);
    y0 = min(max(y0, 0), HSZ - 1);
    const int y1 = min(y0 + 1, HSZ - 1);
    const float wy  = srcy - (float)y0;
    const float wyc = 1.0f - wy;

    const float* __restrict__ row0 = x + ((size_t)img * HSZ + (size_t)y0) * HSZ;
    const float* __restrict__ row1 = x + ((size_t)img * HSZ + (size_t)y1) * HSZ;

    float4 res;
    float* rp = reinterpret_cast<float*>(&res);

#pragma unroll
    for (int j = 0; j < 4; ++j) {
        const int sx = q * 4 + j;
        float srcx = (xo + (float)sx + 0.5f) * scale - 0.5f;
        srcx = fmaxf(srcx, 0.0f);
        int x0 = (int)floorf(srcx);
        x0 = min(max(x0, 0), HSZ - 1);
        const float wx = srcx - (float)x0;

        // Load the consecutive pair [x0c, x0c+1]; at the clamp edge (x0==511)
        // shift the window left so the high element is still the right v01
        // (x1 == min(x0+1,511) == x0c+1 in ALL cases).
        const int x0c = min(x0, HSZ - 2);
        float2 t2, b2;
        __builtin_memcpy(&t2, row0 + x0c, sizeof(float2));  // align-4 safe dwordx2
        __builtin_memcpy(&b2, row1 + x0c, sizeof(float2));

        const bool edge = (x0 == HSZ - 1);
        const float v00 = edge ? t2.y : t2.x;
        const float v10 = edge ? b2.y : b2.x;
        const float v01 = t2.y;
        const float v11 = b2.y;

        // rows = top*(1-wy) + bot*wy; out = rows[x0]*(1-wx) + rows[x1]*wx
        const float left  = v00 * wyc + v10 * wy;
        const float right = v01 * wyc + v11 * wy;
        rp[j] = left * (1.0f - wx) + right * wx;
    }

    reinterpret_cast<float4*>(out)[tid] = res;
}

extern "C" void kernel_launch(void* const* d_in, const int* in_sizes, int n_in,
                              void* d_out, int out_size, void* d_ws, size_t ws_size,
                              hipStream_t stream) {
    const float* x         = (const float*)d_in[0];
    const int*   cam_views = (const int*)  d_in[1];
    const float* resize    = (const float*)d_in[2];
    const float* y_off     = (const float*)d_in[3];
    const float* x_off     = (const float*)d_in[4];
    float* out = (float*)d_out;

    const int block = 256;
    const int grid  = TOTAL_THREADS / block;  // 18,816 exactly, no tail

    crop_prompter_kernel<<<grid, block, 0, stream>>>(
        x, cam_views, resize, y_off, x_off, out);
}